// Round 2
// baseline (10.142 us; speedup 1.0000x reference)
//
#include <hip/hip_runtime.h>

// out[i] = int32( uint(a[i]) XOR uint(b[i]) )
// a,b are exact non-negative integers < 2^20 stored in float32.
// The reference's bit-extract + SwiGLU-multiply XOR reduces exactly to
// integer XOR. JAX x64 is disabled, so the reference's int64 output is
// actually int32 — the harness reads d_out as int32.
__global__ void __launch_bounds__(256) xor_i32_kernel(
    const float* __restrict__ a,
    const float* __restrict__ b,
    int* __restrict__ out,
    int n)
{
    int i = (blockIdx.x * blockDim.x + threadIdx.x) * 4;
    if (i + 3 < n) {
        float4 va = *reinterpret_cast<const float4*>(a + i);
        float4 vb = *reinterpret_cast<const float4*>(b + i);
        int4 vo;
        vo.x = ((int)va.x) ^ ((int)vb.x);
        vo.y = ((int)va.y) ^ ((int)vb.y);
        vo.z = ((int)va.z) ^ ((int)vb.z);
        vo.w = ((int)va.w) ^ ((int)vb.w);
        *reinterpret_cast<int4*>(out + i) = vo;
    } else if (i < n) {
        for (; i < n; ++i) {
            out[i] = ((int)a[i]) ^ ((int)b[i]);
        }
    }
}

extern "C" void kernel_launch(void* const* d_in, const int* in_sizes, int n_in,
                              void* d_out, int out_size, void* d_ws, size_t ws_size,
                              hipStream_t stream)
{
    const float* a = (const float*)d_in[0];
    const float* b = (const float*)d_in[1];
    int* out = (int*)d_out;
    int n = in_sizes[0];

    int elems4 = (n + 3) / 4;              // number of 4-element work items
    int block = 256;
    int grid = (elems4 + block - 1) / block;
    xor_i32_kernel<<<grid, block, 0, stream>>>(a, b, out, n);
}